// Round 1
// baseline (640.016 us; speedup 1.0000x reference)
//
#include <hip/hip_runtime.h>
#include <cmath>

#define NB 2
#define SEQ 2048
#define DIM 512
#define NH 8
#define DEPTH 64

// ---------------------------------------------------------------------------
// Kernel 1: fused QKV projection.  Y = X @ W + b, written to [B,H,S,D] layout.
// grid: (DIM/64, (NB*SEQ)/64, 3)   block: 256
// ---------------------------------------------------------------------------
__global__ __launch_bounds__(256) void qkv_proj_kernel(
    const float* __restrict__ X,
    const float* __restrict__ Wq, const float* __restrict__ bq,
    const float* __restrict__ Wk, const float* __restrict__ bk,
    const float* __restrict__ Wv, const float* __restrict__ bv,
    float* __restrict__ Qo, float* __restrict__ Ko, float* __restrict__ Vo)
{
    const float* W; const float* bias; float* O;
    if (blockIdx.z == 0)      { W = Wq; bias = bq; O = Qo; }
    else if (blockIdx.z == 1) { W = Wk; bias = bk; O = Ko; }
    else                      { W = Wv; bias = bv; O = Vo; }

    __shared__ float As[64][17];
    __shared__ float Bs[16][65];

    const int tid = threadIdx.x;
    const int tx = tid & 15;
    const int ty = tid >> 4;
    const int rowBase = blockIdx.y * 64;   // over B*S
    const int colBase = blockIdx.x * 64;   // over DIM (= h*64+d)

    float acc[4][4] = {};

    for (int k0 = 0; k0 < DIM; k0 += 16) {
        #pragma unroll
        for (int i = 0; i < 4; ++i) {
            int idx = tid + i * 256;
            int r = idx >> 4, c = idx & 15;
            As[r][c] = X[(size_t)(rowBase + r) * DIM + k0 + c];
        }
        #pragma unroll
        for (int i = 0; i < 4; ++i) {
            int idx = tid + i * 256;
            int r = idx >> 6, c = idx & 63;
            Bs[r][c] = W[(size_t)(k0 + r) * DIM + colBase + c];
        }
        __syncthreads();
        #pragma unroll
        for (int kk = 0; kk < 16; ++kk) {
            float a[4], b[4];
            #pragma unroll
            for (int i = 0; i < 4; ++i) a[i] = As[ty * 4 + i][kk];
            #pragma unroll
            for (int j = 0; j < 4; ++j) b[j] = Bs[kk][tx * 4 + j];
            #pragma unroll
            for (int i = 0; i < 4; ++i)
                #pragma unroll
                for (int j = 0; j < 4; ++j)
                    acc[i][j] += a[i] * b[j];
        }
        __syncthreads();
    }

    #pragma unroll
    for (int i = 0; i < 4; ++i) {
        int row = rowBase + ty * 4 + i;        // b*S + s
        int b = row / SEQ, s = row % SEQ;
        #pragma unroll
        for (int j = 0; j < 4; ++j) {
            int col = colBase + tx * 4 + j;    // h*DEPTH + d
            int h = col / DEPTH, d = col % DEPTH;
            O[(((size_t)(b * NH + h) * SEQ) + s) * DEPTH + d] = acc[i][j] + bias[col];
        }
    }
}

// ---------------------------------------------------------------------------
// Kernel 2: logits[q,k] = (Q[q,:]·K[k,:]) / 8 + mask[k]*(-1e9), raw (pre-softmax)
// grid: (SEQ/64, SEQ/64, NB*NH)   block: 256
// ---------------------------------------------------------------------------
__global__ __launch_bounds__(256) void logits_kernel(
    const float* __restrict__ Q, const float* __restrict__ K,
    const float* __restrict__ mask, float* __restrict__ attn)
{
    const int bh = blockIdx.z;
    const int b  = bh / NH;
    const float* Qb = Q + (size_t)bh * SEQ * DEPTH;
    const float* Kb = K + (size_t)bh * SEQ * DEPTH;
    float* Ab = attn + (size_t)bh * SEQ * SEQ;

    __shared__ float Qs[64][65];
    __shared__ float Ks[64][65];

    const int tid = threadIdx.x;
    const int tx = tid & 15;
    const int ty = tid >> 4;
    const int qBase = blockIdx.y * 64;
    const int kBase = blockIdx.x * 64;

    #pragma unroll
    for (int i = 0; i < 16; ++i) {
        int idx = tid + i * 256;
        int r = idx >> 6, c = idx & 63;
        Qs[r][c] = Qb[(size_t)(qBase + r) * DEPTH + c];
        Ks[r][c] = Kb[(size_t)(kBase + r) * DEPTH + c];
    }
    __syncthreads();

    float acc[4][4] = {};
    #pragma unroll 8
    for (int d = 0; d < DEPTH; ++d) {
        float a[4], bb[4];
        #pragma unroll
        for (int i = 0; i < 4; ++i) a[i] = Qs[ty * 4 + i][d];
        #pragma unroll
        for (int j = 0; j < 4; ++j) bb[j] = Ks[tx * 4 + j][d];
        #pragma unroll
        for (int i = 0; i < 4; ++i)
            #pragma unroll
            for (int j = 0; j < 4; ++j)
                acc[i][j] += a[i] * bb[j];
    }

    #pragma unroll
    for (int i = 0; i < 4; ++i) {
        int q = qBase + ty * 4 + i;
        #pragma unroll
        for (int j = 0; j < 4; ++j) {
            int k = kBase + tx * 4 + j;
            float m = mask[b * SEQ + k];
            Ab[(size_t)q * SEQ + k] = acc[i][j] * 0.125f + m * (-1e9f);
        }
    }
}

// ---------------------------------------------------------------------------
// Kernel 3: row softmax over attn, in place.  grid: NB*NH*SEQ blocks, 256 thr
// ---------------------------------------------------------------------------
__global__ __launch_bounds__(256) void softmax_kernel(float* __restrict__ attn)
{
    float* p = attn + (size_t)blockIdx.x * SEQ;
    const int tid = threadIdx.x;

    float vals[8];
    float m = -INFINITY;
    #pragma unroll
    for (int i = 0; i < 8; ++i) {
        vals[i] = p[tid + i * 256];
        m = fmaxf(m, vals[i]);
    }

    __shared__ float red[256];
    red[tid] = m;
    __syncthreads();
    for (int s = 128; s > 0; s >>= 1) {
        if (tid < s) red[tid] = fmaxf(red[tid], red[tid + s]);
        __syncthreads();
    }
    m = red[0];
    __syncthreads();

    float sum = 0.f;
    #pragma unroll
    for (int i = 0; i < 8; ++i) {
        vals[i] = expf(vals[i] - m);
        sum += vals[i];
    }
    red[tid] = sum;
    __syncthreads();
    for (int s = 128; s > 0; s >>= 1) {
        if (tid < s) red[tid] += red[tid + s];
        __syncthreads();
    }
    const float inv = 1.0f / red[0];

    #pragma unroll
    for (int i = 0; i < 8; ++i)
        p[tid + i * 256] = vals[i] * inv;
}

// ---------------------------------------------------------------------------
// Kernel 4: ctx = attn @ V, written to [B,S,DIM] layout.
// grid: (1, SEQ/64, NB*NH)   block: 256
// ---------------------------------------------------------------------------
__global__ __launch_bounds__(256) void ctx_kernel(
    const float* __restrict__ attn, const float* __restrict__ V,
    float* __restrict__ ctx)
{
    const int bh = blockIdx.z;
    const int b = bh / NH, h = bh % NH;
    const float* Ab = attn + (size_t)bh * SEQ * SEQ;
    const float* Vb = V + (size_t)bh * SEQ * DEPTH;

    __shared__ float As[64][17];
    __shared__ float Bs[16][65];

    const int tid = threadIdx.x;
    const int tx = tid & 15;
    const int ty = tid >> 4;
    const int qBase = blockIdx.y * 64;

    float acc[4][4] = {};

    for (int k0 = 0; k0 < SEQ; k0 += 16) {
        #pragma unroll
        for (int i = 0; i < 4; ++i) {
            int idx = tid + i * 256;
            int r = idx >> 4, c = idx & 15;
            As[r][c] = Ab[(size_t)(qBase + r) * SEQ + k0 + c];
        }
        #pragma unroll
        for (int i = 0; i < 4; ++i) {
            int idx = tid + i * 256;
            int r = idx >> 6, c = idx & 63;
            Bs[r][c] = Vb[(size_t)(k0 + r) * DEPTH + c];
        }
        __syncthreads();
        #pragma unroll
        for (int kk = 0; kk < 16; ++kk) {
            float a[4], bb[4];
            #pragma unroll
            for (int i = 0; i < 4; ++i) a[i] = As[ty * 4 + i][kk];
            #pragma unroll
            for (int j = 0; j < 4; ++j) bb[j] = Bs[kk][tx * 4 + j];
            #pragma unroll
            for (int i = 0; i < 4; ++i)
                #pragma unroll
                for (int j = 0; j < 4; ++j)
                    acc[i][j] += a[i] * bb[j];
        }
        __syncthreads();
    }

    #pragma unroll
    for (int i = 0; i < 4; ++i) {
        int q = qBase + ty * 4 + i;
        #pragma unroll
        for (int j = 0; j < 4; ++j) {
            int d = tx * 4 + j;
            ctx[((size_t)(b * SEQ + q)) * DIM + h * DEPTH + d] = acc[i][j];
        }
    }
}

// ---------------------------------------------------------------------------
// Kernel 5: out = ctx @ Wo + bo   ([B*S, DIM] x [DIM, DIM])
// grid: (DIM/64, (NB*SEQ)/64)   block: 256
// ---------------------------------------------------------------------------
__global__ __launch_bounds__(256) void out_proj_kernel(
    const float* __restrict__ ctx, const float* __restrict__ Wo,
    const float* __restrict__ bo, float* __restrict__ out)
{
    __shared__ float As[64][17];
    __shared__ float Bs[16][65];

    const int tid = threadIdx.x;
    const int tx = tid & 15;
    const int ty = tid >> 4;
    const int rowBase = blockIdx.y * 64;
    const int colBase = blockIdx.x * 64;

    float acc[4][4] = {};

    for (int k0 = 0; k0 < DIM; k0 += 16) {
        #pragma unroll
        for (int i = 0; i < 4; ++i) {
            int idx = tid + i * 256;
            int r = idx >> 4, c = idx & 15;
            As[r][c] = ctx[(size_t)(rowBase + r) * DIM + k0 + c];
        }
        #pragma unroll
        for (int i = 0; i < 4; ++i) {
            int idx = tid + i * 256;
            int r = idx >> 6, c = idx & 63;
            Bs[r][c] = Wo[(size_t)(k0 + r) * DIM + colBase + c];
        }
        __syncthreads();
        #pragma unroll
        for (int kk = 0; kk < 16; ++kk) {
            float a[4], bb[4];
            #pragma unroll
            for (int i = 0; i < 4; ++i) a[i] = As[ty * 4 + i][kk];
            #pragma unroll
            for (int j = 0; j < 4; ++j) bb[j] = Bs[kk][tx * 4 + j];
            #pragma unroll
            for (int i = 0; i < 4; ++i)
                #pragma unroll
                for (int j = 0; j < 4; ++j)
                    acc[i][j] += a[i] * bb[j];
        }
        __syncthreads();
    }

    #pragma unroll
    for (int i = 0; i < 4; ++i) {
        int row = rowBase + ty * 4 + i;
        #pragma unroll
        for (int j = 0; j < 4; ++j) {
            int col = colBase + tx * 4 + j;
            out[(size_t)row * DIM + col] = acc[i][j] + bo[col];
        }
    }
}

// ---------------------------------------------------------------------------
extern "C" void kernel_launch(void* const* d_in, const int* in_sizes, int n_in,
                              void* d_out, int out_size, void* d_ws, size_t ws_size,
                              hipStream_t stream)
{
    const float* X    = (const float*)d_in[0];
    const float* mask = (const float*)d_in[1];
    const float* Wq   = (const float*)d_in[2];
    const float* bq   = (const float*)d_in[3];
    const float* Wk   = (const float*)d_in[4];
    const float* bk   = (const float*)d_in[5];
    const float* Wv   = (const float*)d_in[6];
    const float* bv   = (const float*)d_in[7];
    const float* Wo   = (const float*)d_in[8];
    const float* bo   = (const float*)d_in[9];

    float* out  = (float*)d_out;                              // [B,S,DIM]
    float* attn = out + (size_t)NB * SEQ * DIM;               // [B,H,S,S]

    const size_t bhsd = (size_t)NB * NH * SEQ * DEPTH;        // 2,097,152
    float* Q   = (float*)d_ws;
    float* K   = Q + bhsd;
    float* V   = K + bhsd;
    float* ctx = V + bhsd;                                    // [B,S,DIM]

    qkv_proj_kernel<<<dim3(DIM / 64, (NB * SEQ) / 64, 3), 256, 0, stream>>>(
        X, Wq, bq, Wk, bk, Wv, bv, Q, K, V);

    logits_kernel<<<dim3(SEQ / 64, SEQ / 64, NB * NH), 256, 0, stream>>>(
        Q, K, mask, attn);

    softmax_kernel<<<dim3(NB * NH * SEQ), 256, 0, stream>>>(attn);

    ctx_kernel<<<dim3(1, SEQ / 64, NB * NH), 256, 0, stream>>>(attn, V, ctx);

    out_proj_kernel<<<dim3(DIM / 64, (NB * SEQ) / 64), 256, 0, stream>>>(
        ctx, Wo, bo, out);
}

// Round 2
// 414.913 us; speedup vs baseline: 1.5425x; 1.5425x over previous
//
#include <hip/hip_runtime.h>
#include <cmath>

#define NB 2
#define SEQ 2048
#define DIM 512
#define NH 8
#define DEPTH 64

typedef __bf16 bf16_t;
typedef __bf16 bf16x8 __attribute__((ext_vector_type(8)));
typedef float f32x4 __attribute__((ext_vector_type(4)));

// ---------------------------------------------------------------------------
// Kernel 1: fused QKV projection (fp32 GEMM), epilogue emits bf16 hi/lo splits.
//   Q,K -> [B*H, S, 64] (hi, lo separate);  V -> transposed [B*H, 64, S] hi/lo.
// grid: (DIM/64, (NB*SEQ)/64, 3)   block: 256
// ---------------------------------------------------------------------------
__global__ __launch_bounds__(256) void qkv_proj_kernel(
    const float* __restrict__ X,
    const float* __restrict__ Wq, const float* __restrict__ bq,
    const float* __restrict__ Wk, const float* __restrict__ bk,
    const float* __restrict__ Wv, const float* __restrict__ bv,
    bf16_t* __restrict__ qhi, bf16_t* __restrict__ qlo,
    bf16_t* __restrict__ khi, bf16_t* __restrict__ klo,
    bf16_t* __restrict__ vth, bf16_t* __restrict__ vtl)
{
    const float* W; const float* bias;
    if (blockIdx.z == 0)      { W = Wq; bias = bq; }
    else if (blockIdx.z == 1) { W = Wk; bias = bk; }
    else                      { W = Wv; bias = bv; }

    __shared__ float As[64][17];
    __shared__ float Bs[16][65];

    const int tid = threadIdx.x;
    const int tx = tid & 15;
    const int ty = tid >> 4;
    const int rowBase = blockIdx.y * 64;   // over B*S
    const int colBase = blockIdx.x * 64;   // over DIM (= h*64+d)

    float acc[4][4] = {};

    for (int k0 = 0; k0 < DIM; k0 += 16) {
        #pragma unroll
        for (int i = 0; i < 4; ++i) {
            int idx = tid + i * 256;
            int r = idx >> 4, c = idx & 15;
            As[r][c] = X[(size_t)(rowBase + r) * DIM + k0 + c];
        }
        #pragma unroll
        for (int i = 0; i < 4; ++i) {
            int idx = tid + i * 256;
            int r = idx >> 6, c = idx & 63;
            Bs[r][c] = W[(size_t)(k0 + r) * DIM + colBase + c];
        }
        __syncthreads();
        #pragma unroll
        for (int kk = 0; kk < 16; ++kk) {
            float a[4], b[4];
            #pragma unroll
            for (int i = 0; i < 4; ++i) a[i] = As[ty * 4 + i][kk];
            #pragma unroll
            for (int j = 0; j < 4; ++j) b[j] = Bs[kk][tx * 4 + j];
            #pragma unroll
            for (int i = 0; i < 4; ++i)
                #pragma unroll
                for (int j = 0; j < 4; ++j)
                    acc[i][j] += a[i] * b[j];
        }
        __syncthreads();
    }

    const int h = colBase >> 6;   // colBase is 64-aligned -> one head per block-col
    #pragma unroll
    for (int i = 0; i < 4; ++i) {
        int row = rowBase + ty * 4 + i;        // b*S + s
        int b = row >> 11, s = row & (SEQ - 1);
        int bh = b * NH + h;
        #pragma unroll
        for (int j = 0; j < 4; ++j) {
            int d = tx * 4 + j;
            float val = acc[i][j] + bias[(h << 6) + d];
            bf16_t hi = (bf16_t)val;
            bf16_t lo = (bf16_t)(val - (float)hi);
            if (blockIdx.z == 0) {
                size_t o = ((size_t)bh * SEQ + s) * DEPTH + d;
                qhi[o] = hi; qlo[o] = lo;
            } else if (blockIdx.z == 1) {
                size_t o = ((size_t)bh * SEQ + s) * DEPTH + d;
                khi[o] = hi; klo[o] = lo;
            } else {
                size_t o = ((size_t)bh * DEPTH + d) * SEQ + s;
                vth[o] = hi; vtl[o] = lo;
            }
        }
    }
}

// ---------------------------------------------------------------------------
// Kernel 2: fused flash-style attention with MFMA (bf16 hi/lo split = 3 terms).
// Two passes over K-tiles: pass 0 = online max/sum; pass 1 = recompute logits,
// write normalized attn (fp32, nontemporal) + accumulate ctx = P@V.
// grid: 256 (XCD-swizzled over bh, qtile)   block: 256 (4 waves, 32 q-rows each)
// ---------------------------------------------------------------------------
#define MFMA(a, b, c) __builtin_amdgcn_mfma_f32_16x16x32_bf16((a), (b), (c), 0, 0, 0)

__global__ __launch_bounds__(256, 2) void attn_fused_kernel(
    const bf16_t* __restrict__ qhi, const bf16_t* __restrict__ qlo,
    const bf16_t* __restrict__ khi, const bf16_t* __restrict__ klo,
    const bf16_t* __restrict__ vth, const bf16_t* __restrict__ vtl,
    const float* __restrict__ mask,
    float* __restrict__ attn, float* __restrict__ ctx)
{
    __shared__ bf16_t Kh[64][72];
    __shared__ bf16_t Kl[64][72];
    __shared__ bf16_t Vh[64][72];   // [d][key]
    __shared__ bf16_t Vl[64][72];
    __shared__ float mask_s[64];
    __shared__ float p_lds[4][16][68];   // per-wave P staging (one 16-row stripe)

    const int tid  = threadIdx.x;
    const int w    = tid >> 6;
    const int lane = tid & 63;
    const int l15  = lane & 15;
    const int g4   = lane >> 4;

    // XCD-bijective swizzle: blocks on the same XCD share a bh (K/V L2-resident)
    int id  = blockIdx.x;
    int nid = (id & 7) * 32 + (id >> 3);
    const int bh = nid >> 4;      // 16 bh
    const int qt = nid & 15;      // 16 q-tiles of 128
    const int b  = bh >> 3;
    const int h  = bh & 7;

    const size_t kvb = (size_t)bh * SEQ * DEPTH;
    const bf16_t* khi_p = khi + kvb;
    const bf16_t* klo_p = klo + kvb;
    const bf16_t* vth_p = vth + kvb;          // [64][SEQ]
    const bf16_t* vtl_p = vtl + kvb;
    const float*  mask_p = mask + b * SEQ;
    float* attn_p = attn + (size_t)bh * SEQ * SEQ;

    const int qbase = qt * 128 + w * 32;      // wave's first q row

    // Q fragments in registers: 2 stripes x {hi,lo} x 2 k-chunks
    bf16x8 qh[2][2], ql[2][2];
    #pragma unroll
    for (int st = 0; st < 2; ++st) {
        int row = qbase + st * 16 + l15;
        const bf16_t* qr  = qhi + kvb + (size_t)row * DEPTH;
        const bf16_t* qr2 = qlo + kvb + (size_t)row * DEPTH;
        #pragma unroll
        for (int kk = 0; kk < 2; ++kk) {
            qh[st][kk] = *(const bf16x8*)(qr  + kk * 32 + g4 * 8);
            ql[st][kk] = *(const bf16x8*)(qr2 + kk * 32 + g4 * 8);
        }
    }

    float m[2][4], lsum[2][4], invl[2][4];
    #pragma unroll
    for (int st = 0; st < 2; ++st)
        #pragma unroll
        for (int r = 0; r < 4; ++r) { m[st][r] = -INFINITY; lsum[st][r] = 0.f; }

    f32x4 cacc[2][4];
    #pragma unroll
    for (int st = 0; st < 2; ++st)
        #pragma unroll
        for (int nt = 0; nt < 4; ++nt) cacc[st][nt] = (f32x4){0.f, 0.f, 0.f, 0.f};

    for (int pass = 0; pass < 2; ++pass) {
        for (int kt = 0; kt < SEQ / 64; ++kt) {
            const int kbase = kt * 64;
            // ---- stage K (and V in pass 1) tiles + mask ----
            #pragma unroll
            for (int i = 0; i < 2; ++i) {
                int c = tid + i * 256;
                int row = c >> 3, cb = (c & 7) * 8;
                *(uint4*)&Kh[row][cb] = *(const uint4*)(khi_p + (size_t)(kbase + row) * DEPTH + cb);
                *(uint4*)&Kl[row][cb] = *(const uint4*)(klo_p + (size_t)(kbase + row) * DEPTH + cb);
                if (pass) {
                    *(uint4*)&Vh[row][cb] = *(const uint4*)(vth_p + (size_t)row * SEQ + kbase + cb);
                    *(uint4*)&Vl[row][cb] = *(const uint4*)(vtl_p + (size_t)row * SEQ + kbase + cb);
                }
            }
            if (tid < 64) mask_s[tid] = mask_p[kbase + tid];
            __syncthreads();

            // ---- QK^T: S = Qhi*Khi + Qlo*Khi + Qhi*Klo ----
            f32x4 sa[2][4];
            #pragma unroll
            for (int nt = 0; nt < 4; ++nt) {
                int krow = nt * 16 + l15;
                bf16x8 kh0 = *(const bf16x8*)&Kh[krow][g4 * 8];
                bf16x8 kh1 = *(const bf16x8*)&Kh[krow][32 + g4 * 8];
                bf16x8 kl0 = *(const bf16x8*)&Kl[krow][g4 * 8];
                bf16x8 kl1 = *(const bf16x8*)&Kl[krow][32 + g4 * 8];
                #pragma unroll
                for (int st = 0; st < 2; ++st) {
                    f32x4 c = (f32x4){0.f, 0.f, 0.f, 0.f};
                    c = MFMA(qh[st][0], kh0, c);
                    c = MFMA(qh[st][1], kh1, c);
                    c = MFMA(ql[st][0], kh0, c);
                    c = MFMA(ql[st][1], kh1, c);
                    c = MFMA(qh[st][0], kl0, c);
                    c = MFMA(qh[st][1], kl1, c);
                    sa[st][nt] = c;
                }
            }

            if (pass == 0) {
                // ---- online max / sum ----
                #pragma unroll
                for (int st = 0; st < 2; ++st) {
                    float sv[4][4];
                    #pragma unroll
                    for (int nt = 0; nt < 4; ++nt) {
                        float mv = mask_s[nt * 16 + l15] * (-1e9f);
                        #pragma unroll
                        for (int r = 0; r < 4; ++r)
                            sv[nt][r] = sa[st][nt][r] * 0.125f + mv;
                    }
                    #pragma unroll
                    for (int r = 0; r < 4; ++r) {
                        float rm = fmaxf(fmaxf(sv[0][r], sv[1][r]), fmaxf(sv[2][r], sv[3][r]));
                        rm = fmaxf(rm, __shfl_xor(rm, 1));
                        rm = fmaxf(rm, __shfl_xor(rm, 2));
                        rm = fmaxf(rm, __shfl_xor(rm, 4));
                        rm = fmaxf(rm, __shfl_xor(rm, 8));
                        float mn = fmaxf(m[st][r], rm);
                        float ts = __expf(sv[0][r] - mn) + __expf(sv[1][r] - mn)
                                 + __expf(sv[2][r] - mn) + __expf(sv[3][r] - mn);
                        ts += __shfl_xor(ts, 1);
                        ts += __shfl_xor(ts, 2);
                        ts += __shfl_xor(ts, 4);
                        ts += __shfl_xor(ts, 8);
                        lsum[st][r] = lsum[st][r] * __expf(m[st][r] - mn) + ts;
                        m[st][r] = mn;
                    }
                }
            } else {
                // ---- finalize p, write attn, accumulate ctx += P@V ----
                #pragma unroll
                for (int st = 0; st < 2; ++st) {
                    #pragma unroll
                    for (int nt = 0; nt < 4; ++nt) {
                        float mv = mask_s[nt * 16 + l15] * (-1e9f);
                        #pragma unroll
                        for (int r = 0; r < 4; ++r) {
                            float s = sa[st][nt][r] * 0.125f + mv;
                            float p = __expf(s - m[st][r]) * invl[st][r];
                            int qrow = qbase + st * 16 + g4 * 4 + r;
                            __builtin_nontemporal_store(
                                p, &attn_p[(size_t)qrow * SEQ + kbase + nt * 16 + l15]);
                            p_lds[w][g4 * 4 + r][nt * 16 + l15] = p;
                        }
                    }
                    asm volatile("s_waitcnt lgkmcnt(0)" ::: "memory");
                    __builtin_amdgcn_sched_barrier(0);
                    #pragma unroll
                    for (int kk = 0; kk < 2; ++kk) {
                        const float* pr = &p_lds[w][l15][kk * 32 + g4 * 8];
                        f32x4 p0 = *(const f32x4*)pr;
                        f32x4 p1 = *(const f32x4*)(pr + 4);
                        bf16x8 ph, pl;
                        #pragma unroll
                        for (int j = 0; j < 4; ++j) {
                            bf16_t h0 = (bf16_t)p0[j];
                            bf16_t h1 = (bf16_t)p1[j];
                            ph[j]     = h0;
                            ph[j + 4] = h1;
                            pl[j]     = (bf16_t)(p0[j] - (float)h0);
                            pl[j + 4] = (bf16_t)(p1[j] - (float)h1);
                        }
                        #pragma unroll
                        for (int nt = 0; nt < 4; ++nt) {
                            int vrow = nt * 16 + l15;
                            bf16x8 vh = *(const bf16x8*)&Vh[vrow][kk * 32 + g4 * 8];
                            bf16x8 vl = *(const bf16x8*)&Vl[vrow][kk * 32 + g4 * 8];
                            f32x4 c = cacc[st][nt];
                            c = MFMA(ph, vh, c);
                            c = MFMA(pl, vh, c);
                            c = MFMA(ph, vl, c);
                            cacc[st][nt] = c;
                        }
                    }
                }
            }
            __syncthreads();
        }
        if (pass == 0) {
            #pragma unroll
            for (int st = 0; st < 2; ++st)
                #pragma unroll
                for (int r = 0; r < 4; ++r) invl[st][r] = 1.0f / lsum[st][r];
        }
    }

    // ---- write ctx [B,S,DIM] ----
    #pragma unroll
    for (int st = 0; st < 2; ++st)
        #pragma unroll
        for (int nt = 0; nt < 4; ++nt)
            #pragma unroll
            for (int r = 0; r < 4; ++r) {
                int qrow = qbase + st * 16 + g4 * 4 + r;
                ctx[((size_t)(b * SEQ + qrow)) * DIM + (h << 6) + nt * 16 + l15] =
                    cacc[st][nt][r];
            }
}

// ---------------------------------------------------------------------------
// Kernel 3: out = ctx @ Wo + bo   ([B*S, DIM] x [DIM, DIM])  (fp32 GEMM)
// ---------------------------------------------------------------------------
__global__ __launch_bounds__(256) void out_proj_kernel(
    const float* __restrict__ ctx, const float* __restrict__ Wo,
    const float* __restrict__ bo, float* __restrict__ out)
{
    __shared__ float As[64][17];
    __shared__ float Bs[16][65];

    const int tid = threadIdx.x;
    const int tx = tid & 15;
    const int ty = tid >> 4;
    const int rowBase = blockIdx.y * 64;
    const int colBase = blockIdx.x * 64;

    float acc[4][4] = {};

    for (int k0 = 0; k0 < DIM; k0 += 16) {
        #pragma unroll
        for (int i = 0; i < 4; ++i) {
            int idx = tid + i * 256;
            int r = idx >> 4, c = idx & 15;
            As[r][c] = ctx[(size_t)(rowBase + r) * DIM + k0 + c];
        }
        #pragma unroll
        for (int i = 0; i < 4; ++i) {
            int idx = tid + i * 256;
            int r = idx >> 6, c = idx & 63;
            Bs[r][c] = Wo[(size_t)(k0 + r) * DIM + colBase + c];
        }
        __syncthreads();
        #pragma unroll
        for (int kk = 0; kk < 16; ++kk) {
            float a[4], bb[4];
            #pragma unroll
            for (int i = 0; i < 4; ++i) a[i] = As[ty * 4 + i][kk];
            #pragma unroll
            for (int j = 0; j < 4; ++j) bb[j] = Bs[kk][tx * 4 + j];
            #pragma unroll
            for (int i = 0; i < 4; ++i)
                #pragma unroll
                for (int j = 0; j < 4; ++j)
                    acc[i][j] += a[i] * bb[j];
        }
        __syncthreads();
    }

    #pragma unroll
    for (int i = 0; i < 4; ++i) {
        int row = rowBase + ty * 4 + i;
        #pragma unroll
        for (int j = 0; j < 4; ++j) {
            int col = colBase + tx * 4 + j;
            out[(size_t)row * DIM + col] = acc[i][j] + bo[col];
        }
    }
}

// ---------------------------------------------------------------------------
extern "C" void kernel_launch(void* const* d_in, const int* in_sizes, int n_in,
                              void* d_out, int out_size, void* d_ws, size_t ws_size,
                              hipStream_t stream)
{
    const float* X    = (const float*)d_in[0];
    const float* mask = (const float*)d_in[1];
    const float* Wq   = (const float*)d_in[2];
    const float* bq   = (const float*)d_in[3];
    const float* Wk   = (const float*)d_in[4];
    const float* bk   = (const float*)d_in[5];
    const float* Wv   = (const float*)d_in[6];
    const float* bv   = (const float*)d_in[7];
    const float* Wo   = (const float*)d_in[8];
    const float* bo   = (const float*)d_in[9];

    float* out  = (float*)d_out;                          // [B,S,DIM]
    float* attn = out + (size_t)NB * SEQ * DIM;           // [B,H,S,S]

    const size_t N = (size_t)NB * NH * SEQ * DEPTH;       // 2,097,152
    bf16_t* qhi = (bf16_t*)d_ws;
    bf16_t* qlo = qhi + N;
    bf16_t* khi = qlo + N;
    bf16_t* klo = khi + N;
    bf16_t* vth = klo + N;
    bf16_t* vtl = vth + N;
    float*  ctx = (float*)(vtl + N);                      // [B,S,DIM], 8 MB

    qkv_proj_kernel<<<dim3(DIM / 64, (NB * SEQ) / 64, 3), 256, 0, stream>>>(
        X, Wq, bq, Wk, bk, Wv, bv, qhi, qlo, khi, klo, vth, vtl);

    attn_fused_kernel<<<dim3(256), 256, 0, stream>>>(
        qhi, qlo, khi, klo, vth, vtl, mask, attn, ctx);

    out_proj_kernel<<<dim3(DIM / 64, (NB * SEQ) / 64), 256, 0, stream>>>(
        ctx, Wo, bo, out);
}

// Round 3
// 379.632 us; speedup vs baseline: 1.6859x; 1.0929x over previous
//
#include <hip/hip_runtime.h>
#include <cmath>

#define NB 2
#define SEQ 2048
#define DIM 512
#define NH 8
#define DEPTH 64

typedef _Float16 f16_t;
typedef _Float16 f16x8 __attribute__((ext_vector_type(8)));
typedef float f32x4 __attribute__((ext_vector_type(4)));

#define MFMA16(a, b, c) __builtin_amdgcn_mfma_f32_16x16x32_f16((a), (b), (c), 0, 0, 0)

// ---------------------------------------------------------------------------
// Kernel 1: W prep — transpose W[k][n] -> WT[n][k] as fp16.
// Wq/Wk/Wv -> wt rows [z*512+n], Wo -> wot. grid 256 (z4 x kt8 x nt8), block 256
// ---------------------------------------------------------------------------
__global__ __launch_bounds__(256) void wprep_kernel(
    const float* __restrict__ Wq, const float* __restrict__ Wk,
    const float* __restrict__ Wv, const float* __restrict__ Wo,
    f16_t* __restrict__ wt, f16_t* __restrict__ wot)
{
    __shared__ float Ws[64][68];
    const int bx = blockIdx.x;
    const int z  = bx >> 6;
    const int kt = (bx >> 3) & 7;
    const int nt = bx & 7;
    const float* W = (z == 0) ? Wq : (z == 1) ? Wk : (z == 2) ? Wv : Wo;
    const int k0 = kt * 64, n0 = nt * 64;
    const int t = threadIdx.x;
    {
        const int r = t >> 2, c0 = (t & 3) * 16;
        #pragma unroll
        for (int j = 0; j < 4; ++j)
            *(f32x4*)&Ws[r][c0 + j*4] =
                *(const f32x4*)&W[(size_t)(k0 + r) * DIM + n0 + c0 + j*4];
    }
    __syncthreads();
    const int n = t >> 2, kc = (t & 3) * 16;
    f16x8 b0, b1;
    #pragma unroll
    for (int j = 0; j < 8; ++j) {
        b0[j] = (f16_t)Ws[kc + j][n];
        b1[j] = (f16_t)Ws[kc + 8 + j][n];
    }
    f16_t* dst = (z < 3) ? (wt + ((size_t)(z * DIM + n0 + n)) * DIM + k0 + kc)
                         : (wot + (size_t)(n0 + n) * DIM + k0 + kc);
    *(f16x8*)dst = b0;
    *(f16x8*)(dst + 8) = b1;
}

// ---------------------------------------------------------------------------
// Kernel 2: QKV projection as direct-global MFMA GEMM (no LDS).
// C[4096,1536] = X @ [Wq|Wk|Wv] + bias, epilogue -> Q/K hi/lo fp16, V^T fp16.
// grid 384 (32 mb x 12 nb), block 256 (4 waves 2x2, 64x64 per wave)
// ---------------------------------------------------------------------------
__global__ __launch_bounds__(256, 2) void qkv_gemm_kernel(
    const float* __restrict__ X, const f16_t* __restrict__ wt,
    const float* __restrict__ bq, const float* __restrict__ bk,
    const float* __restrict__ bv,
    f16_t* __restrict__ q_h, f16_t* __restrict__ q_l,
    f16_t* __restrict__ k_h, f16_t* __restrict__ k_l,
    f16_t* __restrict__ v_t)
{
    const int bx = blockIdx.x;
    const int mb = bx & 31, nb = bx >> 5;
    const int tid = threadIdx.x;
    const int w = tid >> 6, lane = tid & 63, l15 = lane & 15, g4 = lane >> 4;
    const int mBase = mb * 128 + (w >> 1) * 64;
    const int nBase = nb * 128 + (w & 1) * 64;

    f32x4 acc[4][4];
    #pragma unroll
    for (int i = 0; i < 4; ++i)
        #pragma unroll
        for (int j = 0; j < 4; ++j) acc[i][j] = (f32x4){0.f, 0.f, 0.f, 0.f};

    for (int k0 = 0; k0 < DIM; k0 += 64) {
        f16x8 ah[4][2];
        #pragma unroll
        for (int mt = 0; mt < 4; ++mt) {
            const float* xr = X + (size_t)(mBase + mt*16 + l15) * DIM + k0 + g4*8;
            #pragma unroll
            for (int kk = 0; kk < 2; ++kk) {
                f32x4 v0 = *(const f32x4*)(xr + kk*32);
                f32x4 v1 = *(const f32x4*)(xr + kk*32 + 4);
                f16x8 a;
                #pragma unroll
                for (int j = 0; j < 4; ++j) { a[j] = (f16_t)v0[j]; a[j+4] = (f16_t)v1[j]; }
                ah[mt][kk] = a;
            }
        }
        #pragma unroll
        for (int nt = 0; nt < 4; ++nt) {
            const f16_t* wr = wt + (size_t)(nBase + nt*16 + l15) * DIM + k0 + g4*8;
            #pragma unroll
            for (int kk = 0; kk < 2; ++kk) {
                f16x8 bw = *(const f16x8*)(wr + kk*32);
                #pragma unroll
                for (int mt = 0; mt < 4; ++mt)
                    acc[mt][nt] = MFMA16(ah[mt][kk], bw, acc[mt][nt]);
            }
        }
    }

    const int z = nb >> 2;
    const float* bias = (z == 0) ? bq : (z == 1) ? bk : bv;
    #pragma unroll
    for (int mt = 0; mt < 4; ++mt) {
        #pragma unroll
        for (int nt = 0; nt < 4; ++nt) {
            const int n = nBase + nt*16 + l15;     // 0..1535
            const int col = n & 511;
            const int h = (n >> 6) & 7, d = n & 63;
            const float bb = bias[col];
            #pragma unroll
            for (int r = 0; r < 4; ++r) {
                const int m = mBase + mt*16 + g4*4 + r;
                const int b = m >> 11, s = m & (SEQ - 1);
                const int bh = b * NH + h;
                const float v = acc[mt][nt][r] + bb;
                if (z == 2) {
                    v_t[((size_t)bh * DEPTH + d) * SEQ + s] = (f16_t)v;
                } else {
                    const f16_t hi = (f16_t)v;
                    const f16_t lo = (f16_t)(v - (float)hi);
                    const size_t o = ((size_t)bh * SEQ + s) * DEPTH + d;
                    if (z == 0) { q_h[o] = hi; q_l[o] = lo; }
                    else        { k_h[o] = hi; k_l[o] = lo; }
                }
            }
        }
    }
}

// ---------------------------------------------------------------------------
// Kernel 3: fused two-pass flash attention, direct-global fragments, split-K.
// Block 512 thr = 8 waves = 4 q-stripes x 2 K-halves. grid 512 (16 bh x 32 qt).
// Q/K hi/lo fp16 (3-term QK^T), V/P single fp16 (1-term PV).
// ---------------------------------------------------------------------------
__global__ __launch_bounds__(512, 4) void attn_kernel(
    const f16_t* __restrict__ q_h, const f16_t* __restrict__ q_l,
    const f16_t* __restrict__ k_h, const f16_t* __restrict__ k_l,
    const f16_t* __restrict__ v_t, const float* __restrict__ mask,
    float* __restrict__ attn, f16_t* __restrict__ ctxf)
{
    __shared__ float p_lds[8][16][69];
    __shared__ float ml_lds[8][16][2];
    __shared__ float cx_lds[4][16][68];

    const int tid = threadIdx.x, w = tid >> 6, lane = tid & 63;
    const int l15 = lane & 15, g4 = lane >> 4;
    const int stripe = w >> 1, khalf = w & 1;

    const int id  = blockIdx.x;
    const int nid = (id & 7) * 64 + (id >> 3);   // XCD-contiguous
    const int bh = nid >> 5, qt = nid & 31;
    const int b = bh >> 3, h = bh & 7;

    const size_t kvb = (size_t)bh * SEQ * DEPTH;
    const f16_t* khp = k_h + kvb;
    const f16_t* klp = k_l + kvb;
    const f16_t* vtp = v_t + kvb;
    const float* mp  = mask + b * SEQ;
    float* attn_p = attn + (size_t)bh * SEQ * SEQ;

    const int qbase = qt * 64 + stripe * 16;

    f16x8 qhf[2], qlf[2];
    {
        const f16_t* qr  = q_h + kvb + (size_t)(qbase + l15) * DEPTH + g4*8;
        const f16_t* qr2 = q_l + kvb + (size_t)(qbase + l15) * DEPTH + g4*8;
        qhf[0] = *(const f16x8*)qr;  qhf[1] = *(const f16x8*)(qr + 32);
        qlf[0] = *(const f16x8*)qr2; qlf[1] = *(const f16x8*)(qr2 + 32);
    }

    float m_r[4], l_r[4], invl[4];
    #pragma unroll
    for (int r = 0; r < 4; ++r) { m_r[r] = -INFINITY; l_r[r] = 0.f; }
    f32x4 cacc[4];
    #pragma unroll
    for (int nt = 0; nt < 4; ++nt) cacc[nt] = (f32x4){0.f, 0.f, 0.f, 0.f};

    const int kt0 = khalf * 16, kt1 = kt0 + 16;

    // ---------------- pass 0: online max/sum over this K-half ----------------
    for (int kt = kt0; kt < kt1; ++kt) {
        const int kbase = kt * 64;
        f32x4 sa[4];
        float mbias[4];
        #pragma unroll
        for (int nt = 0; nt < 4; ++nt) {
            const size_t ko = (size_t)(kbase + nt*16 + l15) * DEPTH + g4*8;
            f16x8 kh0 = *(const f16x8*)(khp + ko);
            f16x8 kh1 = *(const f16x8*)(khp + ko + 32);
            f16x8 kl0 = *(const f16x8*)(klp + ko);
            f16x8 kl1 = *(const f16x8*)(klp + ko + 32);
            mbias[nt] = mp[kbase + nt*16 + l15] * (-1e9f);
            __builtin_amdgcn_s_setprio(1);
            f32x4 c = (f32x4){0.f, 0.f, 0.f, 0.f};
            c = MFMA16(qhf[0], kh0, c); c = MFMA16(qhf[1], kh1, c);
            c = MFMA16(qlf[0], kh0, c); c = MFMA16(qlf[1], kh1, c);
            c = MFMA16(qhf[0], kl0, c); c = MFMA16(qhf[1], kl1, c);
            __builtin_amdgcn_s_setprio(0);
            sa[nt] = c;
        }
        float sv[4][4];
        #pragma unroll
        for (int nt = 0; nt < 4; ++nt)
            #pragma unroll
            for (int r = 0; r < 4; ++r)
                sv[nt][r] = sa[nt][r] * 0.125f + mbias[nt];
        #pragma unroll
        for (int r = 0; r < 4; ++r) {
            float rm = fmaxf(fmaxf(sv[0][r], sv[1][r]), fmaxf(sv[2][r], sv[3][r]));
            rm = fmaxf(rm, __shfl_xor(rm, 1));
            rm = fmaxf(rm, __shfl_xor(rm, 2));
            rm = fmaxf(rm, __shfl_xor(rm, 4));
            rm = fmaxf(rm, __shfl_xor(rm, 8));
            const float mn = fmaxf(m_r[r], rm);
            float ts = __expf(sv[0][r] - mn) + __expf(sv[1][r] - mn)
                     + __expf(sv[2][r] - mn) + __expf(sv[3][r] - mn);
            ts += __shfl_xor(ts, 1); ts += __shfl_xor(ts, 2);
            ts += __shfl_xor(ts, 4); ts += __shfl_xor(ts, 8);
            l_r[r] = l_r[r] * __expf(m_r[r] - mn) + ts;
            m_r[r] = mn;
        }
    }

    // ---------------- merge m/l across the two K-half waves ----------------
    if (l15 == 0) {
        #pragma unroll
        for (int r = 0; r < 4; ++r) {
            ml_lds[w][g4*4 + r][0] = m_r[r];
            ml_lds[w][g4*4 + r][1] = l_r[r];
        }
    }
    __syncthreads();
    #pragma unroll
    for (int r = 0; r < 4; ++r) {
        const float mo  = ml_lds[w ^ 1][g4*4 + r][0];
        const float lo_ = ml_lds[w ^ 1][g4*4 + r][1];
        const float mn = fmaxf(m_r[r], mo);
        const float lt = l_r[r] * __expf(m_r[r] - mn) + lo_ * __expf(mo - mn);
        m_r[r] = mn;
        invl[r] = 1.0f / lt;
    }

    // ---------------- pass 1: recompute, write attn, accumulate PV ----------------
    for (int kt = kt0; kt < kt1; ++kt) {
        const int kbase = kt * 64;
        f32x4 sa[4];
        float mbias[4];
        #pragma unroll
        for (int nt = 0; nt < 4; ++nt) {
            const size_t ko = (size_t)(kbase + nt*16 + l15) * DEPTH + g4*8;
            f16x8 kh0 = *(const f16x8*)(khp + ko);
            f16x8 kh1 = *(const f16x8*)(khp + ko + 32);
            f16x8 kl0 = *(const f16x8*)(klp + ko);
            f16x8 kl1 = *(const f16x8*)(klp + ko + 32);
            mbias[nt] = mp[kbase + nt*16 + l15] * (-1e9f);
            __builtin_amdgcn_s_setprio(1);
            f32x4 c = (f32x4){0.f, 0.f, 0.f, 0.f};
            c = MFMA16(qhf[0], kh0, c); c = MFMA16(qhf[1], kh1, c);
            c = MFMA16(qlf[0], kh0, c); c = MFMA16(qlf[1], kh1, c);
            c = MFMA16(qhf[0], kl0, c); c = MFMA16(qhf[1], kl1, c);
            __builtin_amdgcn_s_setprio(0);
            sa[nt] = c;
        }
        #pragma unroll
        for (int nt = 0; nt < 4; ++nt) {
            #pragma unroll
            for (int r = 0; r < 4; ++r) {
                const float s = sa[nt][r] * 0.125f + mbias[nt];
                const float p = __expf(s - m_r[r]) * invl[r];
                const int qrow = qbase + g4*4 + r;
                __builtin_nontemporal_store(
                    p, &attn_p[(size_t)qrow * SEQ + kbase + nt*16 + l15]);
                p_lds[w][g4*4 + r][nt*16 + l15] = p;
            }
        }
        asm volatile("s_waitcnt lgkmcnt(0)" ::: "memory");
        __builtin_amdgcn_sched_barrier(0);
        #pragma unroll
        for (int kk = 0; kk < 2; ++kk) {
            const float* pr = &p_lds[w][l15][kk*32 + g4*8];
            f32x4 p0 = *(const f32x4*)pr;
            f32x4 p1 = *(const f32x4*)(pr + 4);
            f16x8 pf;
            #pragma unroll
            for (int j = 0; j < 4; ++j) { pf[j] = (f16_t)p0[j]; pf[j+4] = (f16_t)p1[j]; }
            __builtin_amdgcn_s_setprio(1);
            #pragma unroll
            for (int nt = 0; nt < 4; ++nt) {
                f16x8 vf = *(const f16x8*)(vtp + (size_t)(nt*16 + l15) * SEQ
                                           + kbase + kk*32 + g4*8);
                cacc[nt] = MFMA16(pf, vf, cacc[nt]);
            }
            __builtin_amdgcn_s_setprio(0);
        }
    }

    // ---------------- merge ctx across K-half waves, store fp16 ----------------
    if (khalf == 1) {
        #pragma unroll
        for (int nt = 0; nt < 4; ++nt)
            #pragma unroll
            for (int r = 0; r < 4; ++r)
                cx_lds[stripe][g4*4 + r][nt*16 + l15] = cacc[nt][r];
    }
    __syncthreads();
    if (khalf == 0) {
        #pragma unroll
        for (int nt = 0; nt < 4; ++nt)
            #pragma unroll
            for (int r = 0; r < 4; ++r) {
                const float v = cacc[nt][r] + cx_lds[stripe][g4*4 + r][nt*16 + l15];
                const int q = qbase + g4*4 + r;
                ctxf[((size_t)(b * SEQ + q)) * DIM + (h << 6) + nt*16 + l15] = (f16_t)v;
            }
    }
}

// ---------------------------------------------------------------------------
// Kernel 4: out = ctx @ Wo + bo, direct-global MFMA (fp16 single).
// grid 256 (64 mb x 4 nb), block 256 (4 waves 2x2, 32x64 per wave)
// ---------------------------------------------------------------------------
__global__ __launch_bounds__(256, 2) void out_gemm_kernel(
    const f16_t* __restrict__ ctxf, const f16_t* __restrict__ wot,
    const float* __restrict__ bo, float* __restrict__ out)
{
    const int bx = blockIdx.x;
    const int mb = bx & 63, nb = bx >> 6;
    const int tid = threadIdx.x;
    const int w = tid >> 6, lane = tid & 63, l15 = lane & 15, g4 = lane >> 4;
    const int mBase = mb * 64 + (w >> 1) * 32;
    const int nBase = nb * 128 + (w & 1) * 64;

    f32x4 acc[2][4];
    #pragma unroll
    for (int i = 0; i < 2; ++i)
        #pragma unroll
        for (int j = 0; j < 4; ++j) acc[i][j] = (f32x4){0.f, 0.f, 0.f, 0.f};

    for (int k0 = 0; k0 < DIM; k0 += 64) {
        f16x8 ah[2][2];
        #pragma unroll
        for (int mt = 0; mt < 2; ++mt) {
            const f16_t* ar = ctxf + (size_t)(mBase + mt*16 + l15) * DIM + k0 + g4*8;
            ah[mt][0] = *(const f16x8*)ar;
            ah[mt][1] = *(const f16x8*)(ar + 32);
        }
        #pragma unroll
        for (int nt = 0; nt < 4; ++nt) {
            const f16_t* wr = wot + (size_t)(nBase + nt*16 + l15) * DIM + k0 + g4*8;
            #pragma unroll
            for (int kk = 0; kk < 2; ++kk) {
                f16x8 bw = *(const f16x8*)(wr + kk*32);
                #pragma unroll
                for (int mt = 0; mt < 2; ++mt)
                    acc[mt][nt] = MFMA16(ah[mt][kk], bw, acc[mt][nt]);
            }
        }
    }
    #pragma unroll
    for (int mt = 0; mt < 2; ++mt) {
        #pragma unroll
        for (int nt = 0; nt < 4; ++nt) {
            const int n = nBase + nt*16 + l15;
            const float bn = bo[n];
            #pragma unroll
            for (int r = 0; r < 4; ++r) {
                const int m = mBase + mt*16 + g4*4 + r;
                out[(size_t)m * DIM + n] = acc[mt][nt][r] + bn;
            }
        }
    }
}

// ---------------------------------------------------------------------------
extern "C" void kernel_launch(void* const* d_in, const int* in_sizes, int n_in,
                              void* d_out, int out_size, void* d_ws, size_t ws_size,
                              hipStream_t stream)
{
    const float* X    = (const float*)d_in[0];
    const float* mask = (const float*)d_in[1];
    const float* Wq   = (const float*)d_in[2];
    const float* bq   = (const float*)d_in[3];
    const float* Wk   = (const float*)d_in[4];
    const float* bk   = (const float*)d_in[5];
    const float* Wv   = (const float*)d_in[6];
    const float* bv   = (const float*)d_in[7];
    const float* Wo   = (const float*)d_in[8];
    const float* bo   = (const float*)d_in[9];

    float* out  = (float*)d_out;                          // [B,S,DIM]
    float* attn = out + (size_t)NB * SEQ * DIM;           // [B,H,S,S]

    const size_t N = (size_t)NB * NH * SEQ * DEPTH;       // 2,097,152
    f16_t* q_h  = (f16_t*)d_ws;
    f16_t* q_l  = q_h + N;
    f16_t* k_h  = q_l + N;
    f16_t* k_l  = k_h + N;
    f16_t* v_t  = k_l + N;
    f16_t* wt   = v_t + N;                                // [1536][512]
    f16_t* wot  = wt + (size_t)3 * DIM * DIM;             // [512][512]
    f16_t* ctxf = wot + (size_t)DIM * DIM;                // [B*S][DIM]

    wprep_kernel<<<256, 256, 0, stream>>>(Wq, Wk, Wv, Wo, wt, wot);

    qkv_gemm_kernel<<<384, 256, 0, stream>>>(X, wt, bq, bk, bv,
                                             q_h, q_l, k_h, k_l, v_t);

    attn_kernel<<<512, 512, 0, stream>>>(q_h, q_l, k_h, k_l, v_t, mask,
                                         attn, ctxf);

    out_gemm_kernel<<<256, 256, 0, stream>>>(ctxf, wot, bo, out);
}